// Round 1
// baseline (2145.387 us; speedup 1.0000x reference)
//
#include <hip/hip_runtime.h>
#include <cstdint>
#include <cstddef>

#define cN0 400000
#define cN1 45056
#define cN2 4096
#define cE0 1126400
#define cE1 102400
#define cD  256

// ---------------- column sums (f64 accumulation) ----------------
__global__ void colsum_f32(const float* __restrict__ x, double* __restrict__ pf,
                           double* __restrict__ pt, int nrows, int ntop) {
    int c = threadIdx.x;  // 256 threads = 256 columns
    double af = 0.0, at = 0.0;
    for (int i = blockIdx.x; i < nrows; i += gridDim.x) {
        double v = (double)x[(size_t)i * cD + c];
        af += v;
        if (i < ntop) at += v;
    }
    pf[(size_t)blockIdx.x * cD + c] = af;
    pt[(size_t)blockIdx.x * cD + c] = at;
}

__global__ void colsum_f64(const double* __restrict__ x, double* __restrict__ pf,
                           double* __restrict__ pt, int nrows, int ntop) {
    int c = threadIdx.x;
    double af = 0.0, at = 0.0;
    for (int i = blockIdx.x; i < nrows; i += gridDim.x) {
        double v = x[(size_t)i * cD + c];
        af += v;
        if (i < ntop) at += v;
    }
    pf[(size_t)blockIdx.x * cD + c] = af;
    pt[(size_t)blockIdx.x * cD + c] = at;
}

__global__ void reduce_mean(const double* __restrict__ p, double* __restrict__ mean,
                            int nblk, double inv) {
    __shared__ double lds[256];
    int c = blockIdx.x;  // one block per column
    double a = 0.0;
    for (int b = threadIdx.x; b < nblk; b += 256) a += p[(size_t)b * cD + c];
    lds[threadIdx.x] = a;
    __syncthreads();
    for (int s = 128; s > 0; s >>= 1) {
        if ((int)threadIdx.x < s) lds[threadIdx.x] += lds[threadIdx.x + s];
        __syncthreads();
    }
    if (threadIdx.x == 0) mean[c] = lds[0] * inv;
}

// ---------------- sign-pack: bit c of row = (x[i][c] > mean[c]) ----------------
__global__ void pack_f32(const float* __restrict__ x, const double* __restrict__ mf_,
                         const double* __restrict__ mt_, unsigned* __restrict__ bf,
                         unsigned* __restrict__ bt, int nrows, int ntop) {
    int c = threadIdx.x, lane = c & 63, w = c >> 6;  // wave w covers cols 64w..64w+63
    double mf = mf_[c], mt = mt_[c];
    for (int i = blockIdx.x; i < nrows; i += gridDim.x) {
        double v = (double)x[(size_t)i * cD + c];
        unsigned long long bl = __ballot(v > mf);
        if (lane == 0) {
            bf[(size_t)i * 8 + 2 * w]     = (unsigned)bl;
            bf[(size_t)i * 8 + 2 * w + 1] = (unsigned)(bl >> 32);
        }
        if (i < ntop) {
            unsigned long long bl2 = __ballot(v > mt);
            if (lane == 0) {
                bt[(size_t)i * 8 + 2 * w]     = (unsigned)bl2;
                bt[(size_t)i * 8 + 2 * w + 1] = (unsigned)(bl2 >> 32);
            }
        }
    }
}

__global__ void pack_f64(const double* __restrict__ x, const double* __restrict__ mf_,
                         const double* __restrict__ mt_, unsigned* __restrict__ bf,
                         unsigned* __restrict__ bt, int nrows, int ntop) {
    int c = threadIdx.x, lane = c & 63, w = c >> 6;
    double mf = mf_[c], mt = mt_[c];
    for (int i = blockIdx.x; i < nrows; i += gridDim.x) {
        double v = x[(size_t)i * cD + c];
        unsigned long long bl = __ballot(v > mf);
        if (lane == 0) {
            bf[(size_t)i * 8 + 2 * w]     = (unsigned)bl;
            bf[(size_t)i * 8 + 2 * w + 1] = (unsigned)(bl >> 32);
        }
        if (i < ntop) {
            unsigned long long bl2 = __ballot(v > mt);
            if (lane == 0) {
                bt[(size_t)i * 8 + 2 * w]     = (unsigned)bl2;
                bt[(size_t)i * 8 + 2 * w + 1] = (unsigned)(bl2 >> 32);
            }
        }
    }
}

// ---------------- CSR build ----------------
__global__ void hist_kernel(const int* __restrict__ dst, int* __restrict__ cnt, int ne) {
    int i = blockIdx.x * blockDim.x + threadIdx.x;
    if (i < ne) atomicAdd(&cnt[dst[i]], 1);
}

__global__ void scan_kernel(const int* __restrict__ cnt, int* __restrict__ rowptr, int n) {
    __shared__ int lds[1024];
    __shared__ int carry;
    if (threadIdx.x == 0) carry = 0;
    __syncthreads();
    for (int base = 0; base < n; base += 1024) {
        int i = base + (int)threadIdx.x;
        int v = (i < n) ? cnt[i] : 0;
        lds[threadIdx.x] = v;
        __syncthreads();
        for (int off = 1; off < 1024; off <<= 1) {
            int t = ((int)threadIdx.x >= off) ? lds[threadIdx.x - off] : 0;
            __syncthreads();
            lds[threadIdx.x] += t;
            __syncthreads();
        }
        int incl = lds[threadIdx.x];
        if (i < n) rowptr[i] = carry + incl - v;   // exclusive
        __syncthreads();
        if (threadIdx.x == 1023) carry += lds[1023];
        __syncthreads();
    }
}

__global__ void fill_kernel(const int* __restrict__ src, const int* __restrict__ dst,
                            const int* __restrict__ rowptr, int* __restrict__ fill,
                            int* __restrict__ adj, int ne) {
    int i = blockIdx.x * blockDim.x + threadIdx.x;
    if (i < ne) {
        int d = dst[i];
        int pos = atomicAdd(&fill[d], 1);
        adj[rowptr[d] + pos] = src[i];
    }
}

// ---------------- aggregation: one wave per target, writes integer sums as f32 ----------------
__global__ void aggregate_kernel(const unsigned* __restrict__ bits, const int* __restrict__ rowptr,
                                 const int* __restrict__ cnt, const int* __restrict__ adj,
                                 float* __restrict__ sout, int ntgt) {
    int wid  = (int)(((size_t)blockIdx.x * blockDim.x + threadIdx.x) >> 6);
    int lane = threadIdx.x & 63;
    if (wid >= ntgt) return;
    int deg = cnt[wid], start = rowptr[wid];
    int wsel = lane >> 3, sh = (lane & 7) * 4;  // lane owns cols 4l..4l+3
    int b0 = 0, b1_ = 0, b2 = 0, b3 = 0;
    for (int e = 0; e < deg; ++e) {
        unsigned v = bits[(size_t)adj[start + e] * 8 + wsel];
        unsigned nib = v >> sh;
        b0 += nib & 1; b1_ += (nib >> 1) & 1; b2 += (nib >> 2) & 1; b3 += (nib >> 3) & 1;
    }
    float4 o;
    o.x = (float)(2 * b0  - deg);
    o.y = (float)(2 * b1_ - deg);
    o.z = (float)(2 * b2  - deg);
    o.w = (float)(2 * b3  - deg);
    ((float4*)sout)[(size_t)wid * 64 + lane] = o;
}

// ---------------- layer-0 GEMM: h = relu((s@W1l)/cnt + xt@W1r + b1), f64 accumulate ----------------
#define GBM 64
#define GBN 64
#define GBK 16
__global__ __launch_bounds__(256) void gemm_layer0(
    const float* __restrict__ s0, const unsigned* __restrict__ xt,
    const int* __restrict__ cnt,
    const float* __restrict__ W1l, const float* __restrict__ W1r,
    const float* __restrict__ b1, double* __restrict__ h) {
    __shared__ float As[GBK][GBM + 4];
    __shared__ float Bs[GBK][GBN + 4];
    int tid = threadIdx.x;
    int tx = tid & 15, ty = tid >> 4;
    int bm0 = blockIdx.x * GBM, bn0 = blockIdx.y * GBN;
    double acc[4][4] = {};
    int a_kk = tid & 15, a_r = tid >> 4;
    int b_n = tid & 63, b_k4 = tid >> 6;
    for (int k0 = 0; k0 < 512; k0 += GBK) {
        #pragma unroll
        for (int r = 0; r < 4; ++r) {
            int row = bm0 + a_r + r * 16;
            int k = k0 + a_kk;
            float v;
            if (k < 256) {
                v = s0[(size_t)row * cD + k];
            } else {
                int kp = k - 256;
                v = ((xt[(size_t)row * 8 + (kp >> 5)] >> (kp & 31)) & 1u) ? 1.0f : -1.0f;
            }
            As[a_kk][a_r + r * 16] = v;
        }
        #pragma unroll
        for (int j = 0; j < 4; ++j) {
            int k = k0 + b_k4 + j * 4;
            float v = (k < 256) ? W1l[(size_t)k * cD + bn0 + b_n]
                                : W1r[(size_t)(k - 256) * cD + bn0 + b_n];
            Bs[b_k4 + j * 4][b_n] = v;
        }
        __syncthreads();
        #pragma unroll
        for (int kk = 0; kk < GBK; ++kk) {
            float4 av = *(const float4*)&As[kk][ty * 4];
            float4 bv = *(const float4*)&Bs[kk][tx * 4];
            double a0 = av.x, a1 = av.y, a2 = av.z, a3 = av.w;
            double w0 = bv.x, w1 = bv.y, w2 = bv.z, w3 = bv.w;
            acc[0][0] += a0 * w0; acc[0][1] += a0 * w1; acc[0][2] += a0 * w2; acc[0][3] += a0 * w3;
            acc[1][0] += a1 * w0; acc[1][1] += a1 * w1; acc[1][2] += a1 * w2; acc[1][3] += a1 * w3;
            acc[2][0] += a2 * w0; acc[2][1] += a2 * w1; acc[2][2] += a2 * w2; acc[2][3] += a2 * w3;
            acc[3][0] += a3 * w0; acc[3][1] += a3 * w1; acc[3][2] += a3 * w2; acc[3][3] += a3 * w3;
        }
        __syncthreads();
        if (k0 == 256 - GBK) {  // finished the s@W1l half -> scale per-row by 1/deg
            #pragma unroll
            for (int i = 0; i < 4; ++i) {
                int row = bm0 + ty * 4 + i;
                int dg = cnt[row];
                double inv = dg > 0 ? 1.0 / (double)dg : 0.0;
                #pragma unroll
                for (int j = 0; j < 4; ++j) acc[i][j] *= inv;
            }
        }
    }
    #pragma unroll
    for (int i = 0; i < 4; ++i) {
        int row = bm0 + ty * 4 + i;
        #pragma unroll
        for (int j = 0; j < 4; ++j) {
            int col = bn0 + tx * 4 + j;
            double v = acc[i][j] + (double)b1[col];
            h[(size_t)row * cD + col] = v > 0.0 ? v : 0.0;
        }
    }
}

// ---------------- final: out = log_softmax((s1/cnt)@W2l + ht@W2r + b2) ----------------
__global__ void final_kernel(const float* __restrict__ s1, const int* __restrict__ cnt1,
                             const unsigned* __restrict__ htb,
                             const float* __restrict__ W2l, const float* __restrict__ W2r,
                             const float* __restrict__ b2, float* __restrict__ out) {
    int row = blockIdx.x;
    int lane = threadIdx.x;  // 64 threads = 1 wave
    __shared__ float ar[256];
    __shared__ float tr[256];
    int deg = cnt1[row];
    float inv = deg > 0 ? 1.0f / (float)deg : 0.0f;
    for (int j = lane; j < 256; j += 64) {
        ar[j] = s1[(size_t)row * cD + j] * inv;
        tr[j] = ((htb[(size_t)row * 8 + (j >> 5)] >> (j & 31)) & 1u) ? 1.0f : -1.0f;
    }
    __syncthreads();
    float acc = 0.0f;
    if (lane < 48) {
        acc = b2[lane];
        for (int j = 0; j < 256; ++j)
            acc += ar[j] * W2l[j * 48 + lane] + tr[j] * W2r[j * 48 + lane];
    }
    float v = (lane < 48) ? acc : -INFINITY;
    float m = v;
    #pragma unroll
    for (int off = 32; off > 0; off >>= 1) m = fmaxf(m, __shfl_xor(m, off));
    float e = (lane < 48) ? expf(acc - m) : 0.0f;
    float ssum = e;
    #pragma unroll
    for (int off = 32; off > 0; off >>= 1) ssum += __shfl_xor(ssum, off);
    if (lane < 48) out[(size_t)row * 48 + lane] = acc - m - logf(ssum);
}

extern "C" void kernel_launch(void* const* d_in, const int* in_sizes, int n_in,
                              void* d_out, int out_size, void* d_ws, size_t ws_size,
                              hipStream_t stream) {
    const float* x   = (const float*)d_in[0];
    const int* src0  = (const int*)d_in[1];
    const int* dst0  = (const int*)d_in[2];
    const int* src1  = (const int*)d_in[3];
    const int* dst1  = (const int*)d_in[4];
    const float* W1l = (const float*)d_in[5];
    const float* b1  = (const float*)d_in[6];
    const float* W1r = (const float*)d_in[7];
    const float* W2l = (const float*)d_in[8];
    const float* b2  = (const float*)d_in[9];
    const float* W2r = (const float*)d_in[10];
    float* out = (float*)d_out;
    (void)in_sizes; (void)n_in; (void)out_size; (void)ws_size;

    char* ws = (char*)d_ws;
    size_t off = 0;
    auto alloc = [&](size_t bytes) -> void* {
        off = (off + 255) & ~(size_t)255;
        void* p = ws + off;
        off += bytes;
        return p;
    };
    double* pf      = (double*)alloc((size_t)1024 * cD * 8);
    double* pt      = (double*)alloc((size_t)1024 * cD * 8);
    double* meanf   = (double*)alloc(cD * 8);
    double* meant   = (double*)alloc(cD * 8);
    double* meanhf  = (double*)alloc(cD * 8);
    double* meanht  = (double*)alloc(cD * 8);
    unsigned* xb    = (unsigned*)alloc((size_t)cN0 * 8 * 4);
    unsigned* xtb   = (unsigned*)alloc((size_t)cN1 * 8 * 4);
    int* cnt0       = (int*)alloc((size_t)cN1 * 4);
    int* rowptr0    = (int*)alloc((size_t)cN1 * 4);
    int* fill0      = (int*)alloc((size_t)cN1 * 4);
    int* adj0       = (int*)alloc((size_t)cE0 * 4);
    float* s0       = (float*)alloc((size_t)cN1 * cD * 4);
    double* h       = (double*)alloc((size_t)cN1 * cD * 8);
    unsigned* hbb   = (unsigned*)alloc((size_t)cN1 * 8 * 4);
    unsigned* htb   = (unsigned*)alloc((size_t)cN2 * 8 * 4);
    int* cnt1       = (int*)alloc((size_t)cN2 * 4);
    int* rowptr1    = (int*)alloc((size_t)cN2 * 4);
    int* fill1      = (int*)alloc((size_t)cN2 * 4);
    int* adj1       = (int*)alloc((size_t)cE1 * 4);
    float* s1       = (float*)alloc((size_t)cN2 * cD * 4);

    hipMemsetAsync(cnt0, 0, (size_t)cN1 * 4, stream);
    hipMemsetAsync(fill0, 0, (size_t)cN1 * 4, stream);
    hipMemsetAsync(cnt1, 0, (size_t)cN2 * 4, stream);
    hipMemsetAsync(fill1, 0, (size_t)cN2 * 4, stream);

    // ---- layer 0 binarization of x ----
    colsum_f32<<<1024, 256, 0, stream>>>(x, pf, pt, cN0, cN1);
    reduce_mean<<<256, 256, 0, stream>>>(pf, meanf, 1024, 1.0 / (double)cN0);
    reduce_mean<<<256, 256, 0, stream>>>(pt, meant, 1024, 1.0 / (double)cN1);
    pack_f32<<<2048, 256, 0, stream>>>(x, meanf, meant, xb, xtb, cN0, cN1);

    // ---- layer 0 CSR + aggregate ----
    hist_kernel<<<(cE0 + 255) / 256, 256, 0, stream>>>(dst0, cnt0, cE0);
    scan_kernel<<<1, 1024, 0, stream>>>(cnt0, rowptr0, cN1);
    fill_kernel<<<(cE0 + 255) / 256, 256, 0, stream>>>(src0, dst0, rowptr0, fill0, adj0, cE0);
    aggregate_kernel<<<cN1 / 4, 256, 0, stream>>>(xb, rowptr0, cnt0, adj0, s0, cN1);

    // ---- layer 0 GEMM (f64 accurate) ----
    gemm_layer0<<<dim3(cN1 / GBM, cD / GBN), 256, 0, stream>>>(s0, xtb, cnt0, W1l, W1r, b1, h);

    // ---- layer 1 binarization of h ----
    colsum_f64<<<512, 256, 0, stream>>>(h, pf, pt, cN1, cN2);
    reduce_mean<<<256, 256, 0, stream>>>(pf, meanhf, 512, 1.0 / (double)cN1);
    reduce_mean<<<256, 256, 0, stream>>>(pt, meanht, 512, 1.0 / (double)cN2);
    pack_f64<<<512, 256, 0, stream>>>(h, meanhf, meanht, hbb, htb, cN1, cN2);

    // ---- layer 1 CSR + aggregate ----
    hist_kernel<<<(cE1 + 255) / 256, 256, 0, stream>>>(dst1, cnt1, cE1);
    scan_kernel<<<1, 1024, 0, stream>>>(cnt1, rowptr1, cN2);
    fill_kernel<<<(cE1 + 255) / 256, 256, 0, stream>>>(src1, dst1, rowptr1, fill1, adj1, cE1);
    aggregate_kernel<<<cN2 / 4, 256, 0, stream>>>(hbb, rowptr1, cnt1, adj1, s1, cN2);

    // ---- final GEMM + log_softmax ----
    final_kernel<<<cN2, 64, 0, stream>>>(s1, cnt1, htb, W2l, W2r, b2, out);
}

// Round 2
// 1714.838 us; speedup vs baseline: 1.2511x; 1.2511x over previous
//
#include <hip/hip_runtime.h>
#include <cstdint>
#include <cstddef>

#define cN0 400000
#define cN1 45056
#define cN2 4096
#define cE0 1126400
#define cE1 102400
#define cNT (cN1 + cN2)       // 49152 unified targets
#define cET (cE0 + cE1)       // 1228800 unified edges

typedef int v4i __attribute__((ext_vector_type(4)));

// ---------------- column sums of x (f64, atomic) ----------------
__global__ void colsum_x(const float* __restrict__ x, double* __restrict__ sumf,
                         double* __restrict__ sumt) {
    int c = threadIdx.x;  // 256 threads = 256 columns
    double af = 0.0, at = 0.0;
    for (int i = blockIdx.x; i < cN0; i += gridDim.x) {
        double v = (double)x[(size_t)i * 256 + c];
        af += v;
        if (i < cN1) at += v;
    }
    atomicAdd(&sumf[c], af);
    atomicAdd(&sumt[c], at);
}

__global__ void colsum_h(const double* __restrict__ h, double* __restrict__ sumf,
                         double* __restrict__ sumt) {
    int c = threadIdx.x;
    double af = 0.0, at = 0.0;
    for (int i = blockIdx.x; i < cN1; i += gridDim.x) {
        double v = h[(size_t)i * 256 + c];
        af += v;
        if (i < cN2) at += v;
    }
    atomicAdd(&sumf[c], af);
    atomicAdd(&sumt[c], at);
}

// ---------------- pack x: bits for all rows + int8 A xt-half (scaled by m) ----------------
__global__ void pack_x(const float* __restrict__ x, const double* __restrict__ sumf,
                       const double* __restrict__ sumt, const int* __restrict__ cntU,
                       unsigned* __restrict__ xb, char* __restrict__ A) {
    int c = threadIdx.x, lane = c & 63, w = c >> 6;
    double mf = sumf[c] * (1.0 / (double)cN0);
    double mt = sumt[c] * (1.0 / (double)cN1);
    for (int i = blockIdx.x; i < cN0; i += gridDim.x) {
        double v = (double)x[(size_t)i * 256 + c];
        unsigned long long bl = __ballot(v > mf);
        if (lane == 0) {
            xb[(size_t)i * 8 + 2 * w]     = (unsigned)bl;
            xb[(size_t)i * 8 + 2 * w + 1] = (unsigned)(bl >> 32);
        }
        if (i < cN1) {
            int dg = cntU[i];
            char m = (char)(dg > 0 ? dg : 1);
            A[(size_t)i * 512 + 256 + c] = (v > mt) ? m : (char)(-m);
        }
    }
}

// ---------------- pack h: bits only ----------------
__global__ void pack_h(const double* __restrict__ h, const double* __restrict__ sumf,
                       const double* __restrict__ sumt, unsigned* __restrict__ hbb,
                       unsigned* __restrict__ htb) {
    int c = threadIdx.x, lane = c & 63, w = c >> 6;
    double mf = sumf[c] * (1.0 / (double)cN1);
    double mt = sumt[c] * (1.0 / (double)cN2);
    for (int i = blockIdx.x; i < cN1; i += gridDim.x) {
        double v = h[(size_t)i * 256 + c];
        unsigned long long bl = __ballot(v > mf);
        if (lane == 0) {
            hbb[(size_t)i * 8 + 2 * w]     = (unsigned)bl;
            hbb[(size_t)i * 8 + 2 * w + 1] = (unsigned)(bl >> 32);
        }
        if (i < cN2) {
            unsigned long long b2 = __ballot(v > mt);
            if (lane == 0) {
                htb[(size_t)i * 8 + 2 * w]     = (unsigned)b2;
                htb[(size_t)i * 8 + 2 * w + 1] = (unsigned)(b2 >> 32);
            }
        }
    }
}

// ---------------- unified CSR build ----------------
__global__ void hist_all(const int* __restrict__ dst0, const int* __restrict__ dst1,
                         int* __restrict__ cntU) {
    int i = blockIdx.x * blockDim.x + threadIdx.x;
    if (i < cE0) atomicAdd(&cntU[dst0[i]], 1);
    else if (i < cET) atomicAdd(&cntU[cN1 + dst1[i - cE0]], 1);
}

__global__ void scan_local(const int* __restrict__ cntU, int* __restrict__ rowptrU,
                           int* __restrict__ btot) {
    __shared__ int lds[1024];
    int b = blockIdx.x, t = threadIdx.x;
    int gi = b * 1024 + t;
    int v = cntU[gi];
    lds[t] = v;
    __syncthreads();
    for (int off = 1; off < 1024; off <<= 1) {
        int tv = (t >= off) ? lds[t - off] : 0;
        __syncthreads();
        lds[t] += tv;
        __syncthreads();
    }
    rowptrU[gi] = lds[t] - v;   // exclusive within block
    if (t == 1023) btot[b] = lds[1023];
}

__global__ void scan_mid(const int* __restrict__ btot, int* __restrict__ boff) {
    if (threadIdx.x == 0) { int s = 0; for (int i = 0; i < 44; ++i) { boff[i] = s; s += btot[i]; } }
    if (threadIdx.x == 1) { int s = 0; for (int i = 44; i < 48; ++i) { boff[i] = s; s += btot[i]; } }
}

__global__ void scan_add(int* __restrict__ rowptrU, const int* __restrict__ boff) {
    int gi = blockIdx.x * 1024 + threadIdx.x;
    rowptrU[gi] += boff[blockIdx.x];
}

__global__ void fill_all(const int* __restrict__ src0, const int* __restrict__ dst0,
                         const int* __restrict__ src1, const int* __restrict__ dst1,
                         const int* __restrict__ rowptrU, int* __restrict__ fillU,
                         int* __restrict__ adjU) {
    int i = blockIdx.x * blockDim.x + threadIdx.x;
    if (i < cE0) {
        int d = dst0[i];
        int pos = atomicAdd(&fillU[d], 1);
        adjU[rowptrU[d] + pos] = src0[i];
    } else if (i < cET) {
        int e = i - cE0;
        int d = cN1 + dst1[e];
        int pos = atomicAdd(&fillU[d], 1);
        adjU[cE0 + rowptrU[d] + pos] = src1[e];
    }
}

// ---------------- aggregation: one wave per target ----------------
__global__ void aggregate0(const unsigned* __restrict__ bits, const int* __restrict__ rowptr,
                           const int* __restrict__ cnt, const int* __restrict__ adj,
                           char* __restrict__ A) {
    int wid  = (int)(((size_t)blockIdx.x * blockDim.x + threadIdx.x) >> 6);
    int lane = threadIdx.x & 63;
    if (wid >= cN1) return;
    int deg = cnt[wid], start = rowptr[wid];
    int wsel = lane >> 3, sh = (lane & 7) * 4;  // lane owns cols 4l..4l+3
    int b0 = 0, b1_ = 0, b2 = 0, b3 = 0;
    for (int e = 0; e < deg; ++e) {
        unsigned v = bits[(size_t)adj[start + e] * 8 + wsel];
        unsigned nib = v >> sh;
        b0 += nib & 1; b1_ += (nib >> 1) & 1; b2 += (nib >> 2) & 1; b3 += (nib >> 3) & 1;
    }
    char4 o;
    o.x = (char)(2 * b0  - deg);
    o.y = (char)(2 * b1_ - deg);
    o.z = (char)(2 * b2  - deg);
    o.w = (char)(2 * b3  - deg);
    *(char4*)(A + (size_t)wid * 512 + lane * 4) = o;
}

__global__ void aggregate1(const unsigned* __restrict__ bits, const int* __restrict__ rowptr,
                           const int* __restrict__ cnt, const int* __restrict__ adj,
                           float* __restrict__ sout) {
    int wid  = (int)(((size_t)blockIdx.x * blockDim.x + threadIdx.x) >> 6);
    int lane = threadIdx.x & 63;
    if (wid >= cN2) return;
    int deg = cnt[wid], start = rowptr[wid];
    int wsel = lane >> 3, sh = (lane & 7) * 4;
    int b0 = 0, b1_ = 0, b2 = 0, b3 = 0;
    for (int e = 0; e < deg; ++e) {
        unsigned v = bits[(size_t)adj[start + e] * 8 + wsel];
        unsigned nib = v >> sh;
        b0 += nib & 1; b1_ += (nib >> 1) & 1; b2 += (nib >> 2) & 1; b3 += (nib >> 3) & 1;
    }
    float4 o;
    o.x = (float)(2 * b0  - deg);
    o.y = (float)(2 * b1_ - deg);
    o.z = (float)(2 * b2  - deg);
    o.w = (float)(2 * b3  - deg);
    ((float4*)sout)[(size_t)wid * 64 + lane] = o;
}

// ---------------- W digit decomposition: Bd[p][n][k] = digit_p(round(W[k][n]*2^31)) ----------------
__global__ void wdigits(const float* __restrict__ W1l, const float* __restrict__ W1r,
                        char* __restrict__ Bd) {
    int idx = blockIdx.x * 256 + threadIdx.x;   // 512*256 total
    int k = idx >> 8, n = idx & 255;
    float w = (k < 256) ? W1l[k * 256 + n] : W1r[(k - 256) * 256 + n];
    long long v = llrint((double)w * 2147483648.0);
    #pragma unroll
    for (int p = 0; p < 3; ++p) {
        int d = (int)((v + 128) & 255) - 128;
        Bd[((size_t)p * 256 + n) * 512 + k] = (char)d;
        v = (v - d) >> 8;
    }
    Bd[((size_t)3 * 256 + n) * 512 + k] = (char)v;   // |v| <= ~14
}

// ---------------- layer-0 GEMM via i8 MFMA, exact digit recombination ----------------
// A [45056][512] i8, Bd [4][256 n][512 k] i8 (k contiguous), out h f64 [45056][256]
__global__ __launch_bounds__(256) void gemm_i8(
    const char* __restrict__ A, const char* __restrict__ Bd,
    const int* __restrict__ cntU, const float* __restrict__ b1,
    double* __restrict__ h) {
    __shared__ __align__(16) char Al[64 * 64];
    __shared__ __align__(16) char Bl[4][64 * 64];
    int tid = threadIdx.x;
    int wv = tid >> 6, lane = tid & 63;
    int bm = blockIdx.x, bn = blockIdx.y;
    // staging coords: thread t covers row r, 16B granule q
    int r = tid >> 2, q = tid & 3;
    int sw = (r >> 1) & 3;
    int ldst = r * 64 + ((q ^ sw) << 4);    // XOR-swizzled LDS byte offset
    const char* Asrc = A + ((size_t)(bm * 64 + r)) * 512 + q * 16;

    v4i acc[4][4];  // [col-tile][plane]
    #pragma unroll
    for (int i = 0; i < 4; ++i)
        #pragma unroll
        for (int j = 0; j < 4; ++j) { v4i z = {0, 0, 0, 0}; acc[i][j] = z; }

    // reader coords
    int arow = wv * 16 + (lane & 15);
    int aq = lane >> 4;
    int a_off = arow * 64 + ((aq ^ ((arow >> 1) & 3)) << 4);
    int bc_ = lane & 15;

    for (int ks = 0; ks < 8; ++ks) {
        v4i av = *(const v4i*)(Asrc + ks * 64);
        v4i bv[4];
        #pragma unroll
        for (int p = 0; p < 4; ++p)
            bv[p] = *(const v4i*)(Bd + (((size_t)p * 256 + bn * 64 + r)) * 512 + ks * 64 + q * 16);
        __syncthreads();    // previous compute done before overwrite
        *(v4i*)(Al + ldst) = av;
        #pragma unroll
        for (int p = 0; p < 4; ++p) *(v4i*)(Bl[p] + ldst) = bv[p];
        __syncthreads();
        v4i af = *(const v4i*)(Al + a_off);
        #pragma unroll
        for (int ct = 0; ct < 4; ++ct) {
            int brow = ct * 16 + bc_;
            int b_off = brow * 64 + ((aq ^ ((brow >> 1) & 3)) << 4);
            #pragma unroll
            for (int p = 0; p < 4; ++p) {
                v4i bf = *(const v4i*)(Bl[p] + b_off);
                acc[ct][p] = __builtin_amdgcn_mfma_i32_16x16x64_i8(af, bf, acc[ct][p], 0, 0, 0);
            }
        }
    }
    // epilogue: T = d3*2^24 + d2*2^16 + d1*2^8 + d0; h = relu(T*2^-31/m + b1)
    int crow0 = bm * 64 + wv * 16 + (lane >> 4) * 4;
    double invm[4];
    #pragma unroll
    for (int i = 0; i < 4; ++i) {
        int cdeg = cntU[crow0 + i];
        invm[i] = 1.0 / (double)(cdeg > 0 ? cdeg : 1);
    }
    #pragma unroll
    for (int ct = 0; ct < 4; ++ct) {
        int col = bn * 64 + ct * 16 + (lane & 15);
        double bcv = (double)b1[col];
        #pragma unroll
        for (int i2 = 0; i2 < 4; ++i2) {
            double T = (double)acc[ct][3][i2] * 16777216.0 + (double)acc[ct][2][i2] * 65536.0
                     + (double)acc[ct][1][i2] * 256.0 + (double)acc[ct][0][i2];
            double hv = T * invm[i2] * 4.6566128730773926e-10 + bcv;
            h[(size_t)(crow0 + i2) * 256 + col] = hv > 0.0 ? hv : 0.0;
        }
    }
}

// ---------------- final: out = log_softmax((s1/m)@W2l + ht@W2r + b2) ----------------
__global__ void final_kernel(const float* __restrict__ s1, const int* __restrict__ cnt1,
                             const unsigned* __restrict__ htb,
                             const float* __restrict__ W2l, const float* __restrict__ W2r,
                             const float* __restrict__ b2, float* __restrict__ out) {
    int row = blockIdx.x;
    int lane = threadIdx.x;  // 64 threads = 1 wave
    __shared__ float ar[256];
    __shared__ float tr[256];
    int deg = cnt1[row];
    float inv = deg > 0 ? 1.0f / (float)deg : 0.0f;
    for (int j = lane; j < 256; j += 64) {
        ar[j] = s1[(size_t)row * 256 + j] * inv;
        tr[j] = ((htb[(size_t)row * 8 + (j >> 5)] >> (j & 31)) & 1u) ? 1.0f : -1.0f;
    }
    __syncthreads();
    float acc = 0.0f;
    if (lane < 48) {
        acc = b2[lane];
        for (int j = 0; j < 256; ++j)
            acc += ar[j] * W2l[j * 48 + lane] + tr[j] * W2r[j * 48 + lane];
    }
    float v = (lane < 48) ? acc : -INFINITY;
    float m = v;
    #pragma unroll
    for (int off = 32; off > 0; off >>= 1) m = fmaxf(m, __shfl_xor(m, off));
    float e = (lane < 48) ? expf(acc - m) : 0.0f;
    float ssum = e;
    #pragma unroll
    for (int off = 32; off > 0; off >>= 1) ssum += __shfl_xor(ssum, off);
    if (lane < 48) out[(size_t)row * 48 + lane] = acc - m - logf(ssum);
}

extern "C" void kernel_launch(void* const* d_in, const int* in_sizes, int n_in,
                              void* d_out, int out_size, void* d_ws, size_t ws_size,
                              hipStream_t stream) {
    const float* x   = (const float*)d_in[0];
    const int* src0  = (const int*)d_in[1];
    const int* dst0  = (const int*)d_in[2];
    const int* src1  = (const int*)d_in[3];
    const int* dst1  = (const int*)d_in[4];
    const float* W1l = (const float*)d_in[5];
    const float* b1  = (const float*)d_in[6];
    const float* W1r = (const float*)d_in[7];
    const float* W2l = (const float*)d_in[8];
    const float* b2  = (const float*)d_in[9];
    const float* W2r = (const float*)d_in[10];
    float* out = (float*)d_out;
    (void)in_sizes; (void)n_in; (void)out_size; (void)ws_size;

    char* ws = (char*)d_ws;
    size_t off = 0;
    auto alloc = [&](size_t bytes) -> void* {
        off = (off + 255) & ~(size_t)255;
        void* p = ws + off;
        off += bytes;
        return p;
    };
    // --- contiguous zero-init region first ---
    char* zero_base = (char*)alloc(0);
    int* cntU       = (int*)alloc((size_t)cNT * 4);
    int* fillU      = (int*)alloc((size_t)cNT * 4);
    double* sumf    = (double*)alloc(256 * 8);
    double* sumt    = (double*)alloc(256 * 8);
    double* sumhf   = (double*)alloc(256 * 8);
    double* sumht   = (double*)alloc(256 * 8);
    size_t zero_bytes = (size_t)((char*)(sumht + 256) - zero_base);
    // --- rest ---
    int* rowptrU    = (int*)alloc((size_t)cNT * 4);
    int* btot       = (int*)alloc(64 * 4);
    int* boff       = (int*)alloc(64 * 4);
    int* adjU       = (int*)alloc((size_t)cET * 4);
    unsigned* xb    = (unsigned*)alloc((size_t)cN0 * 8 * 4);
    char* A         = (char*)alloc((size_t)cN1 * 512);
    char* Bd        = (char*)alloc((size_t)4 * 256 * 512);
    double* h       = (double*)alloc((size_t)cN1 * 256 * 8);
    unsigned* hbb   = (unsigned*)alloc((size_t)cN1 * 8 * 4);
    unsigned* htb   = (unsigned*)alloc((size_t)cN2 * 8 * 4);
    float* s1       = (float*)alloc((size_t)cN2 * 256 * 4);

    hipMemsetAsync(zero_base, 0, zero_bytes, stream);

    // CSR histogram (both layers) + column sums of x
    hist_all<<<cET / 256, 256, 0, stream>>>(dst0, dst1, cntU);
    colsum_x<<<256, 256, 0, stream>>>(x, sumf, sumt);
    // scan (48 blocks exactly cover 49152)
    scan_local<<<48, 1024, 0, stream>>>(cntU, rowptrU, btot);
    scan_mid<<<1, 64, 0, stream>>>(btot, boff);
    scan_add<<<48, 1024, 0, stream>>>(rowptrU, boff);
    // W digits (independent)
    wdigits<<<512, 256, 0, stream>>>(W1l, W1r, Bd);
    // pack x (needs sums + cnt0) -> xb bits + A xt-half
    pack_x<<<1024, 256, 0, stream>>>(x, sumf, sumt, cntU, xb, A);
    // adjacency fill
    fill_all<<<cET / 256, 256, 0, stream>>>(src0, dst0, src1, dst1, rowptrU, fillU, adjU);
    // layer-0 aggregate -> A s-half
    aggregate0<<<cN1 / 4, 256, 0, stream>>>(xb, rowptrU, cntU, adjU, A);
    // layer-0 GEMM (i8 MFMA, exact)
    gemm_i8<<<dim3(cN1 / 64, 4), 256, 0, stream>>>(A, Bd, cntU, b1, h);
    // layer-1 binarization
    colsum_h<<<128, 256, 0, stream>>>(h, sumhf, sumht);
    pack_h<<<512, 256, 0, stream>>>(h, sumhf, sumht, hbb, htb);
    // layer-1 aggregate
    aggregate1<<<cN2 / 4, 256, 0, stream>>>(hbb, rowptrU + cN1, cntU + cN1, adjU + cE0, s1);
    // final GEMM + log_softmax
    final_kernel<<<cN2, 64, 0, stream>>>(s1, cntU + cN1, htb, W2l, W2r, b2, out);
}